// Round 1
// baseline (1471.499 us; speedup 1.0000x reference)
//
#include <hip/hip_runtime.h>
#include <hip/hip_bf16.h>
#include <hip/hip_fp16.h>
#include <stdint.h>

typedef _Float16 hf;
typedef _Float16 h8 __attribute__((ext_vector_type(8)));
typedef _Float16 h4 __attribute__((ext_vector_type(4)));
typedef _Float16 h2 __attribute__((ext_vector_type(2)));
typedef float    f4 __attribute__((ext_vector_type(4)));

__device__ __forceinline__ float celu_f(float x) {
    return x > 0.f ? x : 1.3f * expm1f(x * (1.0f / 1.3f));
}

__device__ __forceinline__ void gload_lds16(const void* g, void* l) {
    __builtin_amdgcn_global_load_lds(
        (const __attribute__((address_space(1))) void*)g,
        (__attribute__((address_space(3))) void*)l, 16, 0, 0);
}

// ---------------------------------------------------------------------------
// transpose + cast f32 -> f16:  dst[c][r] = (hf)src[r][c]
// ---------------------------------------------------------------------------
__global__ __launch_bounds__(256)
void transpose_cast_kernel(const float* __restrict__ src, hf* __restrict__ dst,
                           int R, int C) {
    __shared__ float tile[32][33];
    int nbx = C >> 5;
    int bx = blockIdx.x % nbx, by = blockIdx.x / nbx;
    int c0 = bx << 5, r0 = by << 5;
    int lx = threadIdx.x & 31, ly = threadIdx.x >> 5;   // 32 x 8
#pragma unroll
    for (int i = 0; i < 32; i += 8)
        tile[ly + i][lx] = src[(size_t)(r0 + ly + i) * C + c0 + lx];
    __syncthreads();
#pragma unroll
    for (int i = 0; i < 32; i += 8)
        dst[(size_t)(c0 + ly + i) * R + r0 + lx] = (hf)tile[lx][ly + i];
}

// ---------------------------------------------------------------------------
// small projections: q1 = GN(CELU(query@Wq+bq)), q2 = GN(CELU(query@Wv1+bv1))
// grid 64 = 2 proj x 32 rows, block 256
// ---------------------------------------------------------------------------
__global__ __launch_bounds__(256)
void small_proj_kernel(const float* __restrict__ query,
                       const float* __restrict__ W0, const float* __restrict__ b0,
                       const float* __restrict__ gw0, const float* __restrict__ gb0,
                       const float* __restrict__ W1, const float* __restrict__ b1,
                       const float* __restrict__ gw1, const float* __restrict__ gb1,
                       float* __restrict__ q1, float* __restrict__ q2) {
    int row = blockIdx.x & 31, p = blockIdx.x >> 5;
    const float* W    = p ? W1  : W0;
    const float* bias = p ? b1  : b0;
    const float* gw   = p ? gw1 : gw0;
    const float* gb   = p ? gb1 : gb0;
    float* dst        = p ? q2  : q1;

    __shared__ float s_q[1024];
    __shared__ float s_sum[16], s_sq[16];
    int tid = threadIdx.x, lane = tid & 63, w = tid >> 6;

#pragma unroll
    for (int i = 0; i < 4; ++i) s_q[tid + 256 * i] = query[row * 1024 + tid + 256 * i];
    __syncthreads();

    float acc[4];
#pragma unroll
    for (int j = 0; j < 4; ++j) acc[j] = bias[tid + 256 * j];
    for (int k = 0; k < 1024; ++k) {
        float qk = s_q[k];
        const float* Wr = W + (size_t)k * 1024 + tid;
#pragma unroll
        for (int j = 0; j < 4; ++j) acc[j] = fmaf(qk, Wr[256 * j], acc[j]);
    }
#pragma unroll
    for (int j = 0; j < 4; ++j) acc[j] = celu_f(acc[j]);

    // half-group (64 ch) sums: hg = 4j + w
#pragma unroll
    for (int j = 0; j < 4; ++j) {
        float s = acc[j], q = acc[j] * acc[j];
#pragma unroll
        for (int off = 1; off < 64; off <<= 1) {
            s += __shfl_xor(s, off);
            q += __shfl_xor(q, off);
        }
        if (lane == 0) { s_sum[4 * j + w] = s; s_sq[4 * j + w] = q; }
    }
    __syncthreads();
#pragma unroll
    for (int j = 0; j < 4; ++j) {
        int c = tid + 256 * j;
        int g = c >> 7;
        float mean = (s_sum[2 * g] + s_sum[2 * g + 1]) * (1.f / 128.f);
        float var  = (s_sq[2 * g] + s_sq[2 * g + 1]) * (1.f / 128.f) - mean * mean;
        float rs = rsqrtf(var + 1e-5f);
        dst[row * 1024 + c] = (acc[j] - mean) * rs * gw[c] + gb[c];
    }
}

// ---------------------------------------------------------------------------
// big GEMM + CELU + GroupNorm epilogue.
// X[65536,1024] f32 @ W (given as WT[n][k] f16) -> out [B][H][M][HD] f16
// 128x128 tile, BK=64, 4 waves, double-buffered LDS.
// ---------------------------------------------------------------------------
#define BM 128
#define BN 128
#define BK 64
#define NT 16

__global__ __launch_bounds__(256, 2)
void gemm_proj_kernel(const float* __restrict__ X, const hf* __restrict__ WT,
                      const float* __restrict__ bias,
                      const float* __restrict__ gw, const float* __restrict__ gb,
                      hf* __restrict__ out) {
    __shared__ hf As[2][BM][BK];   // 32 KB
    __shared__ hf Bs[2][BN][BK];   // 32 KB
    // stats scratch aliases As after the main loop (As is dead then)
    float (*s_sum)[BM] = (float (*)[BM])(&As[0][0][0]);
    float (*s_sq)[BM]  = (float (*)[BM])(&As[0][0][0]) + 2;

    const int bid = blockIdx.x;
    // XCD-chunked swizzle: 4096 blocks, 8 XCDs; col-tiles of a row-panel stay
    // on one XCD so the A-panel is read from HBM once.
    const int l  = (bid & 7) * 512 + (bid >> 3);
    const int tm = l >> 3, tn = l & 7;
    const int m0 = tm * BM, n0 = tn * BN;

    const int tid = threadIdx.x;
    const int lane = tid & 63, wid = tid >> 6;
    const int wr = wid >> 1, wc = wid & 1;
    const int l15 = lane & 15, l4 = lane >> 4;

    f4 acc[4][4];
#pragma unroll
    for (int mi = 0; mi < 4; ++mi)
#pragma unroll
        for (int ni = 0; ni < 4; ++ni) acc[mi][ni] = (f4)0.f;

    f4 areg[8];

    auto stageA_load = [&](int t) {
        const float* base = X + (size_t)m0 * 1024 + t * BK;
#pragma unroll
        for (int i = 0; i < 8; ++i) {
            int idx = tid + 256 * i;
            int r = idx >> 4, c4 = idx & 15;
            areg[i] = *(const f4*)(base + (size_t)r * 1024 + c4 * 4);
        }
    };
    auto stageA_write = [&](int buf) {
#pragma unroll
        for (int i = 0; i < 8; ++i) {
            int idx = tid + 256 * i;
            int r = idx >> 4, c4 = idx & 15;
            h4 hv;
            hv[0] = (hf)areg[i][0]; hv[1] = (hf)areg[i][1];
            hv[2] = (hf)areg[i][2]; hv[3] = (hf)areg[i][3];
            *(h4*)&As[buf][r][c4 * 4] = hv;
        }
    };
    auto stageB = [&](int t, int buf) {
        const hf* base = WT + (size_t)n0 * 1024 + t * BK;
#pragma unroll
        for (int i = 0; i < 4; ++i) {
            int idx = tid + 256 * i;
            int r = idx >> 3, c8 = idx & 7;
            gload_lds16(base + (size_t)r * 1024 + c8 * 8,
                        (char*)&Bs[buf][0][0] + idx * 16);
        }
    };
    auto compute = [&](int cur) {
        h8 af[4][2], bf[4][2];
#pragma unroll
        for (int mi = 0; mi < 4; ++mi)
#pragma unroll
            for (int kk = 0; kk < 2; ++kk)
                af[mi][kk] = *(const h8*)&As[cur][wr * 64 + mi * 16 + l15][kk * 32 + l4 * 8];
#pragma unroll
        for (int ni = 0; ni < 4; ++ni)
#pragma unroll
            for (int kk = 0; kk < 2; ++kk)
                bf[ni][kk] = *(const h8*)&Bs[cur][wc * 64 + ni * 16 + l15][kk * 32 + l4 * 8];
#pragma unroll
        for (int kk = 0; kk < 2; ++kk)
#pragma unroll
            for (int mi = 0; mi < 4; ++mi)
#pragma unroll
                for (int ni = 0; ni < 4; ++ni)
                    acc[mi][ni] = __builtin_amdgcn_mfma_f32_16x16x32_f16(
                        af[mi][kk], bf[ni][kk], acc[mi][ni], 0, 0, 0);
    };

    stageA_load(0);
    stageB(0, 0);
    stageA_write(0);
    __syncthreads();
    for (int t = 0; t < NT; ++t) {
        const int cur = t & 1, nxt = cur ^ 1;
        if (t + 1 < NT) { stageA_load(t + 1); stageB(t + 1, nxt); }
        compute(cur);
        if (t + 1 < NT) stageA_write(nxt);
        __syncthreads();
    }

    // ---- epilogue: bias + CELU + GroupNorm(128-wide group == this tile) ----
    float biasv[4], gwv[4], gbv[4];
#pragma unroll
    for (int ni = 0; ni < 4; ++ni) {
        int c = n0 + wc * 64 + ni * 16 + l15;
        biasv[ni] = bias[c]; gwv[ni] = gw[c]; gbv[ni] = gb[c];
    }
#pragma unroll
    for (int mi = 0; mi < 4; ++mi) {
#pragma unroll
        for (int reg = 0; reg < 4; ++reg) {
            float s = 0.f, q = 0.f;
#pragma unroll
            for (int ni = 0; ni < 4; ++ni) {
                float v = acc[mi][ni][reg] + biasv[ni];
                v = celu_f(v);
                acc[mi][ni][reg] = v;
                s += v; q += v * v;
            }
#pragma unroll
            for (int off = 1; off < 16; off <<= 1) {
                s += __shfl_xor(s, off);
                q += __shfl_xor(q, off);
            }
            if (l15 == 0) {
                int R = wr * 64 + mi * 16 + l4 * 4 + reg;
                s_sum[wc][R] = s;
                s_sq[wc][R]  = q;
            }
        }
    }
    __syncthreads();
    const int bb = m0 >> 11;                       // batch index (tile never crosses)
    hf* outbase = out + (((size_t)bb * 8 + tn) * 2048 + (m0 & 2047)) * 128;
#pragma unroll
    for (int mi = 0; mi < 4; ++mi) {
#pragma unroll
        for (int reg = 0; reg < 4; ++reg) {
            int R = wr * 64 + mi * 16 + l4 * 4 + reg;
            float mean = (s_sum[0][R] + s_sum[1][R]) * (1.f / 128.f);
            float var  = (s_sq[0][R] + s_sq[1][R]) * (1.f / 128.f) - mean * mean;
            float rs = rsqrtf(var + 1e-5f);
#pragma unroll
            for (int ni = 0; ni < 4; ++ni) {
                int d = wc * 64 + ni * 16 + l15;
                float y = (acc[mi][ni][reg] - mean) * rs * gwv[ni] + gbv[ni];
                outbase[(size_t)R * 128 + d] = (hf)y;
            }
        }
    }
}

// ---------------------------------------------------------------------------
// SCAtt: one block (256 thr, 4 waves) per (b,h).
// phase1: T=relu((q1 (*) k)@Wm+bm) via MFMA; alpha=T@Ws+bs; pool+=T
// phase2: softmax(alpha); ach=sigmoid(pool/M @ Wc + bc)
// phase3: agg = sum softmax * v; out = q2*agg*ach
// ---------------------------------------------------------------------------
__global__ __launch_bounds__(256)
void attn_kernel(const hf* __restrict__ kp, const hf* __restrict__ vp,
                 const float* __restrict__ q1, const float* __restrict__ q2,
                 const hf* __restrict__ WmT,
                 const float* __restrict__ bm, const float* __restrict__ Wsv,
                 const float* __restrict__ bsv,
                 const float* __restrict__ Wc, const float* __restrict__ bc,
                 float* __restrict__ out) {
    const int bh = blockIdx.x;
    const int b = bh >> 3, h = bh & 7;
    const hf* kbh = kp + (size_t)bh * 2048 * 128;
    const hf* vbh = vp + (size_t)bh * 2048 * 128;

    __shared__ float s_alpha[2048];
    __shared__ float s_pool[4][64];
    __shared__ float s_red[4];
    __shared__ float s_agg[4][128];
    __shared__ float s_ach[128];

    const int tid = threadIdx.x, lane = tid & 63, w = tid >> 6;
    const int l15 = lane & 15, l4 = lane >> 4;

    h8 q1f[4], bfr[4][4];
    float bmv[4], wsw[4];
    const float* q1h = q1 + b * 1024 + h * 128;
#pragma unroll
    for (int kk = 0; kk < 4; ++kk)
#pragma unroll
        for (int j = 0; j < 8; ++j)
            q1f[kk][j] = (hf)q1h[kk * 32 + l4 * 8 + j];
#pragma unroll
    for (int ni = 0; ni < 4; ++ni) {
#pragma unroll
        for (int kk = 0; kk < 4; ++kk)
            bfr[ni][kk] = *(const h8*)(WmT + (size_t)(ni * 16 + l15) * 128 + kk * 32 + l4 * 8);
        bmv[ni] = bm[ni * 16 + l15];
        wsw[ni] = Wsv[ni * 16 + l15];
    }
    const float bs0 = bsv[0];

    float pool_acc[4] = {0.f, 0.f, 0.f, 0.f};
    for (int it = 0; it < 32; ++it) {
        const int mt0 = (it * 4 + w) * 16;
        const hf* kr = kbh + (size_t)(mt0 + l15) * 128 + l4 * 8;
        h8 af[4];
#pragma unroll
        for (int kk = 0; kk < 4; ++kk) {
            h8 kf = *(const h8*)(kr + kk * 32);
            af[kk] = kf * q1f[kk];
        }
        f4 acc[4];
#pragma unroll
        for (int ni = 0; ni < 4; ++ni) acc[ni] = (f4)0.f;
#pragma unroll
        for (int kk = 0; kk < 4; ++kk)
#pragma unroll
            for (int ni = 0; ni < 4; ++ni)
                acc[ni] = __builtin_amdgcn_mfma_f32_16x16x32_f16(af[kk], bfr[ni][kk], acc[ni], 0, 0, 0);
        float apart[4] = {0.f, 0.f, 0.f, 0.f};
#pragma unroll
        for (int ni = 0; ni < 4; ++ni)
#pragma unroll
            for (int reg = 0; reg < 4; ++reg) {
                float tt = fmaxf(acc[ni][reg] + bmv[ni], 0.f);
                apart[reg] += tt * wsw[ni];
                pool_acc[ni] += tt;
            }
#pragma unroll
        for (int reg = 0; reg < 4; ++reg) {
            float a = apart[reg];
            a += __shfl_xor(a, 1); a += __shfl_xor(a, 2);
            a += __shfl_xor(a, 4); a += __shfl_xor(a, 8);
            if (l15 == 0) s_alpha[mt0 + l4 * 4 + reg] = a + bs0;
        }
    }
    // pool: reduce over row-groups within wave, then across waves
#pragma unroll
    for (int ni = 0; ni < 4; ++ni) {
        float pv = pool_acc[ni];
        pv += __shfl_xor(pv, 16); pv += __shfl_xor(pv, 32);
        if (lane < 16) s_pool[w][ni * 16 + lane] = pv;
    }
    __syncthreads();
    if (tid < 64)
        s_pool[0][tid] = (s_pool[0][tid] + s_pool[1][tid] + s_pool[2][tid] + s_pool[3][tid]) * (1.f / 2048.f);
    __syncthreads();
    if (tid < 128) {
        float a = bc[tid];
#pragma unroll 8
        for (int j = 0; j < 64; ++j) a += s_pool[0][j] * Wc[j * 128 + tid];
        s_ach[tid] = 1.f / (1.f + expf(-a));
    }
    // softmax over s_alpha[2048]
    float lm = -1e30f;
#pragma unroll
    for (int i = 0; i < 8; ++i) lm = fmaxf(lm, s_alpha[tid + 256 * i]);
#pragma unroll
    for (int off = 1; off < 64; off <<= 1) lm = fmaxf(lm, __shfl_xor(lm, off));
    if (lane == 0) s_red[w] = lm;
    __syncthreads();
    const float gmax = fmaxf(fmaxf(s_red[0], s_red[1]), fmaxf(s_red[2], s_red[3]));
    float ls = 0.f;
#pragma unroll
    for (int i = 0; i < 8; ++i) {
        int idx = tid + 256 * i;
        float e = expf(s_alpha[idx] - gmax);
        s_alpha[idx] = e;
        ls += e;
    }
#pragma unroll
    for (int off = 1; off < 64; off <<= 1) ls += __shfl_xor(ls, off);
    __syncthreads();
    if (lane == 0) s_red[w] = ls;
    __syncthreads();
    const float inv_sum = 1.f / (s_red[0] + s_red[1] + s_red[2] + s_red[3]);

    // phase 3: weighted V aggregation
    const int c = tid & 63, chunk = tid >> 6;
    const hf* vb = vbh + (size_t)chunk * 512 * 128 + c * 2;
    float a0 = 0.f, a1 = 0.f;
#pragma unroll 4
    for (int m = 0; m < 512; ++m) {
        float p = s_alpha[chunk * 512 + m];
        h2 v = *(const h2*)(vb + (size_t)m * 128);
        a0 = fmaf(p, (float)v[0], a0);
        a1 = fmaf(p, (float)v[1], a1);
    }
    s_agg[chunk][c * 2]     = a0;
    s_agg[chunk][c * 2 + 1] = a1;
    __syncthreads();
    if (tid < 128) {
        float agg = (s_agg[0][tid] + s_agg[1][tid] + s_agg[2][tid] + s_agg[3][tid]) * inv_sum;
        int oc = b * 1024 + h * 128 + tid;
        out[oc] = q2[oc] * agg * s_ach[tid];
    }
}

// ---------------------------------------------------------------------------
extern "C" void kernel_launch(void* const* d_in, const int* in_sizes, int n_in,
                              void* d_out, int out_size, void* d_ws, size_t ws_size,
                              hipStream_t stream) {
    const float* query = (const float*)d_in[0];
    const float* key   = (const float*)d_in[1];
    const float* value = (const float*)d_in[2];
    const float* Wq   = (const float*)d_in[3];
    const float* bq   = (const float*)d_in[4];
    const float* gqw  = (const float*)d_in[5];
    const float* gqb  = (const float*)d_in[6];
    const float* Wv1  = (const float*)d_in[7];
    const float* bv1  = (const float*)d_in[8];
    const float* gv1w = (const float*)d_in[9];
    const float* gv1b = (const float*)d_in[10];
    const float* Wk   = (const float*)d_in[11];
    const float* bk   = (const float*)d_in[12];
    const float* gkw  = (const float*)d_in[13];
    const float* gkb  = (const float*)d_in[14];
    const float* Wv2  = (const float*)d_in[15];
    const float* bv2  = (const float*)d_in[16];
    const float* gv2w = (const float*)d_in[17];
    const float* gv2b = (const float*)d_in[18];
    const float* Wm   = (const float*)d_in[19];
    const float* bm   = (const float*)d_in[20];
    const float* Ws   = (const float*)d_in[21];
    const float* bs   = (const float*)d_in[22];
    const float* Wc   = (const float*)d_in[23];
    const float* bc   = (const float*)d_in[24];
    float* out = (float*)d_out;

    char* ws = (char*)d_ws;
    hf*    kproj = (hf*)(ws);                       // 134,217,728 B
    hf*    vproj = (hf*)(ws + 134217728);           // 134,217,728 B
    float* q1    = (float*)(ws + 268435456);        //     131,072 B
    float* q2    = (float*)(ws + 268566528);        //     131,072 B
    hf*    WkT   = (hf*)(ws + 268697600);           //   2,097,152 B
    hf*    Wv2T  = (hf*)(ws + 270794752);           //   2,097,152 B
    hf*    WmT   = (hf*)(ws + 272891904);           //      16,384 B

    transpose_cast_kernel<<<1024, 256, 0, stream>>>(Wk,  WkT,  1024, 1024);
    transpose_cast_kernel<<<1024, 256, 0, stream>>>(Wv2, Wv2T, 1024, 1024);
    transpose_cast_kernel<<<8,    256, 0, stream>>>(Wm,  WmT,  128,  64);
    small_proj_kernel<<<64, 256, 0, stream>>>(query, Wq, bq, gqw, gqb,
                                              Wv1, bv1, gv1w, gv1b, q1, q2);
    gemm_proj_kernel<<<4096, 256, 0, stream>>>(key,   WkT,  bk,  gkw,  gkb,  kproj);
    gemm_proj_kernel<<<4096, 256, 0, stream>>>(value, Wv2T, bv2, gv2w, gv2b, vproj);
    attn_kernel<<<256, 256, 0, stream>>>(kproj, vproj, q1, q2, WmT,
                                         bm, Ws, bs, Wc, bc, out);
}

// Round 5
// 1136.206 us; speedup vs baseline: 1.2951x; 1.2951x over previous
//
#include <hip/hip_runtime.h>
#include <hip/hip_bf16.h>
#include <hip/hip_fp16.h>
#include <stdint.h>

typedef _Float16 hf;
typedef _Float16 h8 __attribute__((ext_vector_type(8)));
typedef _Float16 h4 __attribute__((ext_vector_type(4)));
typedef _Float16 h2 __attribute__((ext_vector_type(2)));
typedef float    f4 __attribute__((ext_vector_type(4)));

__device__ __forceinline__ float celu_f(float x) {
    return x > 0.f ? x : 1.3f * expm1f(x * (1.0f / 1.3f));
}

__device__ __forceinline__ void gload_lds16(const void* g, void* l) {
    __builtin_amdgcn_global_load_lds(
        (const __attribute__((address_space(1))) void*)g,
        (__attribute__((address_space(3))) void*)l, 16, 0, 0);
}

// ---------------------------------------------------------------------------
// transpose + cast f32 -> f16:  dst[c][r] = (hf)src[r][c]
// ---------------------------------------------------------------------------
__global__ __launch_bounds__(256)
void transpose_cast_kernel(const float* __restrict__ src, hf* __restrict__ dst,
                           int R, int C) {
    __shared__ float tile[32][33];
    int nbx = C >> 5;
    int bx = blockIdx.x % nbx, by = blockIdx.x / nbx;
    int c0 = bx << 5, r0 = by << 5;
    int lx = threadIdx.x & 31, ly = threadIdx.x >> 5;   // 32 x 8
#pragma unroll
    for (int i = 0; i < 32; i += 8)
        tile[ly + i][lx] = src[(size_t)(r0 + ly + i) * C + c0 + lx];
    __syncthreads();
#pragma unroll
    for (int i = 0; i < 32; i += 8)
        dst[(size_t)(c0 + ly + i) * R + r0 + lx] = (hf)tile[lx][ly + i];
}

// ---------------------------------------------------------------------------
// streaming f32 -> f16 convert (16B loads, 16B stores)
// ---------------------------------------------------------------------------
__global__ __launch_bounds__(256)
void conv_f16_kernel(const float* __restrict__ src, hf* __restrict__ dst, int n8) {
    int stride = gridDim.x * 256;
    for (int i = blockIdx.x * 256 + threadIdx.x; i < n8; i += stride) {
        size_t off = (size_t)i * 8;
        f4 a = *(const f4*)(src + off);
        f4 b = *(const f4*)(src + off + 4);
        h8 o;
        o[0] = (hf)a[0]; o[1] = (hf)a[1]; o[2] = (hf)a[2]; o[3] = (hf)a[3];
        o[4] = (hf)b[0]; o[5] = (hf)b[1]; o[6] = (hf)b[2]; o[7] = (hf)b[3];
        *(h8*)(dst + off) = o;
    }
}

// ---------------------------------------------------------------------------
// small projections: q1 = GN(CELU(query@Wq+bq)), q2 = GN(CELU(query@Wv1+bv1))
// grid 256 = 2 proj x 32 rows x 4 col-chunks (GN group 128 stays block-local)
// ---------------------------------------------------------------------------
__global__ __launch_bounds__(256)
void small_proj_kernel(const float* __restrict__ query,
                       const float* __restrict__ W0, const float* __restrict__ b0,
                       const float* __restrict__ gw0, const float* __restrict__ gb0,
                       const float* __restrict__ W1, const float* __restrict__ b1,
                       const float* __restrict__ gw1, const float* __restrict__ gb1,
                       float* __restrict__ q1, float* __restrict__ q2) {
    int bid = blockIdx.x;
    int p = bid & 1, row = (bid >> 1) & 31, qc = bid >> 6;
    const float* W    = p ? W1  : W0;
    const float* bias = p ? b1  : b0;
    const float* gw   = p ? gw1 : gw0;
    const float* gb   = p ? gb1 : gb0;
    float* dst        = p ? q2  : q1;

    __shared__ float s_q[1024];
    __shared__ float s_ws[4], s_wq[4];
    int tid = threadIdx.x, lane = tid & 63, w = tid >> 6;
    int col = qc * 256 + tid;

#pragma unroll
    for (int i = 0; i < 4; ++i) s_q[tid + 256 * i] = query[row * 1024 + tid + 256 * i];
    __syncthreads();

    float acc = bias[col];
#pragma unroll 8
    for (int k = 0; k < 1024; ++k)
        acc = fmaf(s_q[k], W[(size_t)k * 1024 + col], acc);
    acc = celu_f(acc);

    float s = acc, sq = acc * acc;
#pragma unroll
    for (int off = 1; off < 64; off <<= 1) {
        s += __shfl_xor(s, off);
        sq += __shfl_xor(sq, off);
    }
    if (lane == 0) { s_ws[w] = s; s_wq[w] = sq; }
    __syncthreads();
    int lg = tid >> 7;  // local group (global group = 2*qc + lg)
    float mean = (s_ws[2 * lg] + s_ws[2 * lg + 1]) * (1.f / 128.f);
    float var  = (s_wq[2 * lg] + s_wq[2 * lg + 1]) * (1.f / 128.f) - mean * mean;
    float rs = rsqrtf(var + 1e-5f);
    dst[row * 1024 + col] = (acc - mean) * rs * gw[col] + gb[col];
}

// ---------------------------------------------------------------------------
// fast GEMM: A f16 [65536,1024] @ WT f16 [1024(n),1024(k)] + CELU + GroupNorm
// m97 structure: 128x128 tile, BK=64, 4 waves, both operands via
// global_load_lds w=16, single-buffer 2-barrier loop.
// Bank-conflict fix (rule 21): linear LDS dest + XOR-swizzled global source
// slot (c8 ^= r&7) + XOR-swizzled ds_read slot.
// ---------------------------------------------------------------------------
#define BM 128
#define BN 128
#define BK 64
#define NT 16

__global__ __launch_bounds__(256, 2)
void gemm_f16_kernel(const hf* __restrict__ A, const hf* __restrict__ WT,
                     const float* __restrict__ bias,
                     const float* __restrict__ gw, const float* __restrict__ gb,
                     hf* __restrict__ out) {
    __shared__ hf As[BM][BK];   // 16 KB
    __shared__ hf Bs[BN][BK];   // 16 KB
    float (*s_sum)[BM] = (float (*)[BM])(&As[0][0]);
    float (*s_sq)[BM]  = (float (*)[BM])(&As[0][0]) + 2;

    const int bid = blockIdx.x;
    const int l  = (bid & 7) * 512 + (bid >> 3);   // XCD-chunked swizzle (4096 % 8 == 0)
    const int tm = l >> 3, tn = l & 7;
    const int m0 = tm * BM, n0 = tn * BN;

    const int tid = threadIdx.x;
    const int lane = tid & 63, wid = tid >> 6;
    const int wr = wid >> 1, wc = wid & 1;
    const int l15 = lane & 15, l4 = lane >> 4;

    f4 acc[4][4];
#pragma unroll
    for (int mi = 0; mi < 4; ++mi)
#pragma unroll
        for (int ni = 0; ni < 4; ++ni) acc[mi][ni] = (f4)0.f;

    const hf* Abase = A  + (size_t)m0 * 1024;
    const hf* Bbase = WT + (size_t)n0 * 1024;

    // staging slot geometry: idx in [0,1024), r = idx>>3 (tile row), c8 = idx&7
    // (16B slot). Source slot is c8 ^ (r&7); LDS dest stays linear.
    int sr[4], sc[4];
#pragma unroll
    for (int i = 0; i < 4; ++i) {
        int idx = tid + 256 * i;
        sr[i] = idx >> 3;
        sc[i] = (idx & 7) ^ (sr[i] & 7);
    }

    for (int t = 0; t < NT; ++t) {
        const size_t kof = (size_t)t * BK;
#pragma unroll
        for (int i = 0; i < 4; ++i) {
            int idx = tid + 256 * i;
            gload_lds16(Abase + (size_t)sr[i] * 1024 + kof + sc[i] * 8,
                        (char*)&As[0][0] + idx * 16);
            gload_lds16(Bbase + (size_t)sr[i] * 1024 + kof + sc[i] * 8,
                        (char*)&Bs[0][0] + idx * 16);
        }
        __syncthreads();

        h8 af[4][2], bf[4][2];
        const int sx = l15 & 7;   // read-side XOR (row&7)
#pragma unroll
        for (int mi = 0; mi < 4; ++mi)
#pragma unroll
            for (int kk = 0; kk < 2; ++kk) {
                int row = wr * 64 + mi * 16 + l15;
                int slot = (kk * 4 + l4) ^ sx;
                af[mi][kk] = *(const h8*)((const char*)&As[0][0] + row * 128 + slot * 16);
            }
#pragma unroll
        for (int ni = 0; ni < 4; ++ni)
#pragma unroll
            for (int kk = 0; kk < 2; ++kk) {
                int row = wc * 64 + ni * 16 + l15;
                int slot = (kk * 4 + l4) ^ sx;
                bf[ni][kk] = *(const h8*)((const char*)&Bs[0][0] + row * 128 + slot * 16);
            }
#pragma unroll
        for (int kk = 0; kk < 2; ++kk)
#pragma unroll
            for (int mi = 0; mi < 4; ++mi)
#pragma unroll
                for (int ni = 0; ni < 4; ++ni)
                    acc[mi][ni] = __builtin_amdgcn_mfma_f32_16x16x32_f16(
                        af[mi][kk], bf[ni][kk], acc[mi][ni], 0, 0, 0);
        __syncthreads();
    }

    // ---- epilogue: bias + CELU + GroupNorm (group 128 == tile width) ----
    float biasv[4], gwv[4], gbv[4];
#pragma unroll
    for (int ni = 0; ni < 4; ++ni) {
        int c = n0 + wc * 64 + ni * 16 + l15;
        biasv[ni] = bias[c]; gwv[ni] = gw[c]; gbv[ni] = gb[c];
    }
#pragma unroll
    for (int mi = 0; mi < 4; ++mi) {
#pragma unroll
        for (int reg = 0; reg < 4; ++reg) {
            float s = 0.f, q = 0.f;
#pragma unroll
            for (int ni = 0; ni < 4; ++ni) {
                float v = acc[mi][ni][reg] + biasv[ni];
                v = celu_f(v);
                acc[mi][ni][reg] = v;
                s += v; q += v * v;
            }
#pragma unroll
            for (int off = 1; off < 16; off <<= 1) {
                s += __shfl_xor(s, off);
                q += __shfl_xor(q, off);
            }
            if (l15 == 0) {
                int R = wr * 64 + mi * 16 + l4 * 4 + reg;
                s_sum[wc][R] = s;
                s_sq[wc][R]  = q;
            }
        }
    }
    __syncthreads();
    const int bb = m0 >> 11;
    hf* outbase = out + (((size_t)bb * 8 + tn) * 2048 + (m0 & 2047)) * 128;
#pragma unroll
    for (int mi = 0; mi < 4; ++mi) {
#pragma unroll
        for (int reg = 0; reg < 4; ++reg) {
            int R = wr * 64 + mi * 16 + l4 * 4 + reg;
            float mean = (s_sum[0][R] + s_sum[1][R]) * (1.f / 128.f);
            float var  = (s_sq[0][R] + s_sq[1][R]) * (1.f / 128.f) - mean * mean;
            float rs = rsqrtf(var + 1e-5f);
#pragma unroll
            for (int ni = 0; ni < 4; ++ni) {
                int d = wc * 64 + ni * 16 + l15;
                float y = (acc[mi][ni][reg] - mean) * rs * gwv[ni] + gbv[ni];
                outbase[(size_t)R * 128 + d] = (hf)y;
            }
        }
    }
}

// ---------------------------------------------------------------------------
// fallback GEMM (R1, f32 A reg-staged) — used only if ws_size is too small
// for the f16 pre-convert buffer.
// ---------------------------------------------------------------------------
__global__ __launch_bounds__(256, 2)
void gemm_proj_kernel(const float* __restrict__ X, const hf* __restrict__ WT,
                      const float* __restrict__ bias,
                      const float* __restrict__ gw, const float* __restrict__ gb,
                      hf* __restrict__ out) {
    __shared__ hf As[2][BM][BK];
    __shared__ hf Bs[2][BN][BK];
    float (*s_sum)[BM] = (float (*)[BM])(&As[0][0][0]);
    float (*s_sq)[BM]  = (float (*)[BM])(&As[0][0][0]) + 2;

    const int bid = blockIdx.x;
    const int l  = (bid & 7) * 512 + (bid >> 3);
    const int tm = l >> 3, tn = l & 7;
    const int m0 = tm * BM, n0 = tn * BN;

    const int tid = threadIdx.x;
    const int lane = tid & 63, wid = tid >> 6;
    const int wr = wid >> 1, wc = wid & 1;
    const int l15 = lane & 15, l4 = lane >> 4;

    f4 acc[4][4];
#pragma unroll
    for (int mi = 0; mi < 4; ++mi)
#pragma unroll
        for (int ni = 0; ni < 4; ++ni) acc[mi][ni] = (f4)0.f;

    f4 areg[8];
    auto stageA_load = [&](int t) {
        const float* base = X + (size_t)m0 * 1024 + t * BK;
#pragma unroll
        for (int i = 0; i < 8; ++i) {
            int idx = tid + 256 * i;
            int r = idx >> 4, c4 = idx & 15;
            areg[i] = *(const f4*)(base + (size_t)r * 1024 + c4 * 4);
        }
    };
    auto stageA_write = [&](int buf) {
#pragma unroll
        for (int i = 0; i < 8; ++i) {
            int idx = tid + 256 * i;
            int r = idx >> 4, c4 = idx & 15;
            h4 hv;
            hv[0] = (hf)areg[i][0]; hv[1] = (hf)areg[i][1];
            hv[2] = (hf)areg[i][2]; hv[3] = (hf)areg[i][3];
            *(h4*)&As[buf][r][c4 * 4] = hv;
        }
    };
    auto stageB = [&](int t, int buf) {
        const hf* base = WT + (size_t)n0 * 1024 + t * BK;
#pragma unroll
        for (int i = 0; i < 4; ++i) {
            int idx = tid + 256 * i;
            int r = idx >> 3, c8 = idx & 7;
            gload_lds16(base + (size_t)r * 1024 + c8 * 8,
                        (char*)&Bs[buf][0][0] + idx * 16);
        }
    };
    auto compute = [&](int cur) {
        h8 af[4][2], bf[4][2];
#pragma unroll
        for (int mi = 0; mi < 4; ++mi)
#pragma unroll
            for (int kk = 0; kk < 2; ++kk)
                af[mi][kk] = *(const h8*)&As[cur][wr * 64 + mi * 16 + l15][kk * 32 + l4 * 8];
#pragma unroll
        for (int ni = 0; ni < 4; ++ni)
#pragma unroll
            for (int kk = 0; kk < 2; ++kk)
                bf[ni][kk] = *(const h8*)&Bs[cur][wc * 64 + ni * 16 + l15][kk * 32 + l4 * 8];
#pragma unroll
        for (int kk = 0; kk < 2; ++kk)
#pragma unroll
            for (int mi = 0; mi < 4; ++mi)
#pragma unroll
                for (int ni = 0; ni < 4; ++ni)
                    acc[mi][ni] = __builtin_amdgcn_mfma_f32_16x16x32_f16(
                        af[mi][kk], bf[ni][kk], acc[mi][ni], 0, 0, 0);
    };

    stageA_load(0);
    stageB(0, 0);
    stageA_write(0);
    __syncthreads();
    for (int t = 0; t < NT; ++t) {
        const int cur = t & 1, nxt = cur ^ 1;
        if (t + 1 < NT) { stageA_load(t + 1); stageB(t + 1, nxt); }
        compute(cur);
        if (t + 1 < NT) stageA_write(nxt);
        __syncthreads();
    }

    float biasv[4], gwv[4], gbv[4];
#pragma unroll
    for (int ni = 0; ni < 4; ++ni) {
        int c = n0 + wc * 64 + ni * 16 + l15;
        biasv[ni] = bias[c]; gwv[ni] = gw[c]; gbv[ni] = gb[c];
    }
#pragma unroll
    for (int mi = 0; mi < 4; ++mi) {
#pragma unroll
        for (int reg = 0; reg < 4; ++reg) {
            float s = 0.f, q = 0.f;
#pragma unroll
            for (int ni = 0; ni < 4; ++ni) {
                float v = acc[mi][ni][reg] + biasv[ni];
                v = celu_f(v);
                acc[mi][ni][reg] = v;
                s += v; q += v * v;
            }
#pragma unroll
            for (int off = 1; off < 16; off <<= 1) {
                s += __shfl_xor(s, off);
                q += __shfl_xor(q, off);
            }
            if (l15 == 0) {
                int R = wr * 64 + mi * 16 + l4 * 4 + reg;
                s_sum[wc][R] = s;
                s_sq[wc][R]  = q;
            }
        }
    }
    __syncthreads();
    const int bb = m0 >> 11;
    hf* outbase = out + (((size_t)bb * 8 + tn) * 2048 + (m0 & 2047)) * 128;
#pragma unroll
    for (int mi = 0; mi < 4; ++mi) {
#pragma unroll
        for (int reg = 0; reg < 4; ++reg) {
            int R = wr * 64 + mi * 16 + l4 * 4 + reg;
            float mean = (s_sum[0][R] + s_sum[1][R]) * (1.f / 128.f);
            float var  = (s_sq[0][R] + s_sq[1][R]) * (1.f / 128.f) - mean * mean;
            float rs = rsqrtf(var + 1e-5f);
#pragma unroll
            for (int ni = 0; ni < 4; ++ni) {
                int d = wc * 64 + ni * 16 + l15;
                float y = (acc[mi][ni][reg] - mean) * rs * gwv[ni] + gbv[ni];
                outbase[(size_t)R * 128 + d] = (hf)y;
            }
        }
    }
}

// ---------------------------------------------------------------------------
// SCAtt stage 1: alpha (pre-softmax) + pool partials.
// grid 1024 = 256 bh x 4 M-chunks of 512; 256 thr.
// ---------------------------------------------------------------------------
__global__ __launch_bounds__(256)
void attn_alpha_kernel(const hf* __restrict__ kp, const float* __restrict__ q1,
                       const hf* __restrict__ WmT,
                       const float* __restrict__ bm, const float* __restrict__ Wsv,
                       const float* __restrict__ bsv,
                       float* __restrict__ ws_alpha, float* __restrict__ ws_pool) {
    const int bid = blockIdx.x;
    const int bh = bid >> 2, chunk = bid & 3;
    const int b = bh >> 3, h = bh & 7;
    const hf* kbh = kp + (size_t)bh * 2048 * 128;

    __shared__ float s_pool[4][64];
    const int tid = threadIdx.x, lane = tid & 63, w = tid >> 6;
    const int l15 = lane & 15, l4 = lane >> 4;

    h8 q1f[4], bfr[4][4];
    float bmv[4], wsw[4];
    const float* q1h = q1 + b * 1024 + h * 128;
#pragma unroll
    for (int kk = 0; kk < 4; ++kk)
#pragma unroll
        for (int j = 0; j < 8; ++j)
            q1f[kk][j] = (hf)q1h[kk * 32 + l4 * 8 + j];
#pragma unroll
    for (int ni = 0; ni < 4; ++ni) {
#pragma unroll
        for (int kk = 0; kk < 4; ++kk)
            bfr[ni][kk] = *(const h8*)(WmT + (size_t)(ni * 16 + l15) * 128 + kk * 32 + l4 * 8);
        bmv[ni] = bm[ni * 16 + l15];
        wsw[ni] = Wsv[ni * 16 + l15];
    }
    const float bs0 = bsv[0];

    float pool_acc[4] = {0.f, 0.f, 0.f, 0.f};
    for (int it = 0; it < 8; ++it) {
        const int mt0 = chunk * 512 + (it * 4 + w) * 16;
        const hf* kr = kbh + (size_t)(mt0 + l15) * 128 + l4 * 8;
        h8 af[4];
#pragma unroll
        for (int kk = 0; kk < 4; ++kk) {
            h8 kf = *(const h8*)(kr + kk * 32);
            af[kk] = kf * q1f[kk];
        }
        f4 acc[4];
#pragma unroll
        for (int ni = 0; ni < 4; ++ni) acc[ni] = (f4)0.f;
#pragma unroll
        for (int kk = 0; kk < 4; ++kk)
#pragma unroll
            for (int ni = 0; ni < 4; ++ni)
                acc[ni] = __builtin_amdgcn_mfma_f32_16x16x32_f16(af[kk], bfr[ni][kk], acc[ni], 0, 0, 0);
        float apart[4] = {0.f, 0.f, 0.f, 0.f};
#pragma unroll
        for (int ni = 0; ni < 4; ++ni)
#pragma unroll
            for (int reg = 0; reg < 4; ++reg) {
                float tt = fmaxf(acc[ni][reg] + bmv[ni], 0.f);
                apart[reg] += tt * wsw[ni];
                pool_acc[ni] += tt;
            }
#pragma unroll
        for (int reg = 0; reg < 4; ++reg) {
            float a = apart[reg];
            a += __shfl_xor(a, 1); a += __shfl_xor(a, 2);
            a += __shfl_xor(a, 4); a += __shfl_xor(a, 8);
            if (l15 == 0) ws_alpha[bh * 2048 + mt0 + l4 * 4 + reg] = a + bs0;
        }
    }
#pragma unroll
    for (int ni = 0; ni < 4; ++ni) {
        float pv = pool_acc[ni];
        pv += __shfl_xor(pv, 16); pv += __shfl_xor(pv, 32);
        if (lane < 16) s_pool[w][ni * 16 + lane] = pv;
    }
    __syncthreads();
    if (tid < 64)
        ws_pool[bid * 64 + tid] =
            s_pool[0][tid] + s_pool[1][tid] + s_pool[2][tid] + s_pool[3][tid];
}

// ---------------------------------------------------------------------------
// SCAtt stage 2: softmax over M (writes normalized probs in place) + channel
// gate sigmoid(pool@Wc+bc). grid 256 (one per bh).
// ---------------------------------------------------------------------------
__global__ __launch_bounds__(256)
void attn_soft_kernel(float* __restrict__ ws_alpha, const float* __restrict__ ws_pool,
                      const float* __restrict__ Wc, const float* __restrict__ bc,
                      float* __restrict__ ws_ach) {
    const int bh = blockIdx.x;
    __shared__ float s_a[2048];
    __shared__ float s_pool[64];
    __shared__ float s_red[4];
    const int tid = threadIdx.x, lane = tid & 63, w = tid >> 6;
    float* arow = ws_alpha + bh * 2048;

#pragma unroll
    for (int i = 0; i < 8; ++i) s_a[tid + 256 * i] = arow[tid + 256 * i];
    if (tid < 64)
        s_pool[tid] = (ws_pool[(bh * 4 + 0) * 64 + tid] + ws_pool[(bh * 4 + 1) * 64 + tid] +
                       ws_pool[(bh * 4 + 2) * 64 + tid] + ws_pool[(bh * 4 + 3) * 64 + tid]) *
                      (1.f / 2048.f);
    __syncthreads();

    float lm = -1e30f;
#pragma unroll
    for (int i = 0; i < 8; ++i) lm = fmaxf(lm, s_a[tid + 256 * i]);
#pragma unroll
    for (int off = 1; off < 64; off <<= 1) lm = fmaxf(lm, __shfl_xor(lm, off));
    if (lane == 0) s_red[w] = lm;
    __syncthreads();
    const float gmax = fmaxf(fmaxf(s_red[0], s_red[1]), fmaxf(s_red[2], s_red[3]));
    float ls = 0.f;
#pragma unroll
    for (int i = 0; i < 8; ++i) {
        int idx = tid + 256 * i;
        float e = expf(s_a[idx] - gmax);
        s_a[idx] = e;
        ls += e;
    }
#pragma unroll
    for (int off = 1; off < 64; off <<= 1) ls += __shfl_xor(ls, off);
    __syncthreads();
    if (lane == 0) s_red[w] = ls;
    __syncthreads();
    const float inv_sum = 1.f / (s_red[0] + s_red[1] + s_red[2] + s_red[3]);
#pragma unroll
    for (int i = 0; i < 8; ++i) {
        int idx = tid + 256 * i;
        arow[idx] = s_a[idx] * inv_sum;
    }
    if (tid < 128) {
        float a = bc[tid];
#pragma unroll 8
        for (int j = 0; j < 64; ++j) a += s_pool[j] * Wc[j * 128 + tid];
        ws_ach[bh * 128 + tid] = 1.f / (1.f + expf(-a));
    }
}

// ---------------------------------------------------------------------------
// SCAtt stage 3: partial weighted-V aggregation.
// grid 1024 = 256 bh x 4 chunks of 512 rows; 256 thr (4 quarters x 64 h2-pairs)
// ---------------------------------------------------------------------------
__global__ __launch_bounds__(256)
void attn_agg_kernel(const hf* __restrict__ vp, const float* __restrict__ ws_probs,
                     float* __restrict__ ws_aggp) {
    const int bid = blockIdx.x;
    const int bh = bid >> 2, chunk = bid & 3;
    __shared__ float s_p[512];
    __shared__ float s_part[4][128];
    const int tid = threadIdx.x;

    s_p[tid]       = ws_probs[bh * 2048 + chunk * 512 + tid];
    s_p[tid + 256] = ws_probs[bh * 2048 + chunk * 512 + tid + 256];
    __syncthreads();

    const int q = tid >> 6, pr2 = tid & 63;
    const hf* vb = vp + (size_t)bh * 2048 * 128 + (size_t)(chunk * 512 + q * 128) * 128 + pr2 * 2;
    float a0 = 0.f, a1 = 0.f;
#pragma unroll 4
    for (int m = 0; m < 128; ++m) {
        float p = s_p[q * 128 + m];
        h2 v = *(const h2*)(vb + (size_t)m * 128);
        a0 = fmaf(p, (float)v[0], a0);
        a1 = fmaf(p, (float)v[1], a1);
    }
    s_part[q][pr2 * 2]     = a0;
    s_part[q][pr2 * 2 + 1] = a1;
    __syncthreads();
    if (tid < 128)
        ws_aggp[bid * 128 + tid] =
            s_part[0][tid] + s_part[1][tid] + s_part[2][tid] + s_part[3][tid];
}

// ---------------------------------------------------------------------------
// SCAtt stage 4: combine partials, apply q2 * agg * ach. grid 128.
// ---------------------------------------------------------------------------
__global__ __launch_bounds__(256)
void attn_out_kernel(const float* __restrict__ ws_aggp, const float* __restrict__ ws_ach,
                     const float* __restrict__ q2, float* __restrict__ out) {
    const int idx = blockIdx.x * 256 + threadIdx.x;   // 32768 outputs
    const int b = idx >> 10, c = idx & 1023;
    const int h = c >> 7, d = c & 127;
    const int bh = b * 8 + h;
    float agg = ws_aggp[(bh * 4 + 0) * 128 + d] + ws_aggp[(bh * 4 + 1) * 128 + d] +
                ws_aggp[(bh * 4 + 2) * 128 + d] + ws_aggp[(bh * 4 + 3) * 128 + d];
    out[idx] = q2[idx] * agg * ws_ach[bh * 128 + d];
}

// ---------------------------------------------------------------------------
extern "C" void kernel_launch(void* const* d_in, const int* in_sizes, int n_in,
                              void* d_out, int out_size, void* d_ws, size_t ws_size,
                              hipStream_t stream) {
    const float* query = (const float*)d_in[0];
    const float* key   = (const float*)d_in[1];
    const float* value = (const float*)d_in[2];
    const float* Wq   = (const float*)d_in[3];
    const float* bq   = (const float*)d_in[4];
    const float* gqw  = (const float*)d_in[5];
    const float* gqb  = (const float*)d_in[6];
    const float* Wv1  = (const float*)d_in[7];
    const float* bv1  = (const float*)d_in[8];
    const float* gv1w = (const float*)d_in[9];
    const float* gv1b = (const float*)d_in[10];
    const float* Wk   = (const float*)d_in[11];
    const float* bk   = (const float*)d_in[12];
    const float* gkw  = (const float*)d_in[13];
    const float* gkb  = (const float*)d_in[14];
    const float* Wv2  = (const float*)d_in[15];
    const float* bv2  = (const float*)d_in[16];
    const float* gv2w = (const float*)d_in[17];
    const float* gv2b = (const float*)d_in[18];
    const float* Wm   = (const float*)d_in[19];
    const float* bm   = (const float*)d_in[20];
    const float* Ws   = (const float*)d_in[21];
    const float* bs   = (const float*)d_in[22];
    const float* Wc   = (const float*)d_in[23];
    const float* bc   = (const float*)d_in[24];
    float* out = (float*)d_out;

    char* ws = (char*)d_ws;
    const size_t SZ_PROJ = 134217728;   // 65536*1024 hf
    // fast layout
    hf*    kproj = (hf*)(ws);
    hf*    vproj = (hf*)(ws + SZ_PROJ);
    hf*    khvh  = (hf*)(ws + 2 * SZ_PROJ);          // shared f16 staging of key/value
    char*  tail_fast = ws + 3 * SZ_PROJ;
    // fallback layout (no khvh)
    char*  tail_slow = ws + 2 * SZ_PROJ;

    const bool fast = ws_size >= (size_t)(3 * SZ_PROJ + 16 * 1024 * 1024);
    char* tail = fast ? tail_fast : tail_slow;

    float* q1    = (float*)(tail);                     // 131072 B
    float* q2    = (float*)(tail + 131072);            // 131072 B
    hf*    WkT   = (hf*)(tail + 262144);               // 2 MB
    hf*    Wv2T  = (hf*)(tail + 2359296);              // 2 MB
    hf*    WmT   = (hf*)(tail + 4456448);              // 16 KB
    float* wsAlpha = (float*)(tail + 4472832);         // 2 MB  (alpha -> probs)
    float* wsPool  = (float*)(tail + 6569984);         // 256 KB
    float* wsAch   = (float*)(tail + 6832128);         // 128 KB
    float* wsAggp  = (float*)(tail + 6963200);         // 512 KB
    // tail end: 7487488 B

    transpose_cast_kernel<<<1024, 256, 0, stream>>>(Wk,  WkT,  1024, 1024);
    transpose_cast_kernel<<<1024, 256, 0, stream>>>(Wv2, Wv2T, 1024, 1024);
    transpose_cast_kernel<<<8,    256, 0, stream>>>(Wm,  WmT,  128,  64);
    small_proj_kernel<<<256, 256, 0, stream>>>(query, Wq, bq, gqw, gqb,
                                               Wv1, bv1, gv1w, gv1b, q1, q2);
    if (fast) {
        conv_f16_kernel<<<4096, 256, 0, stream>>>(key, khvh, 8388608);
        gemm_f16_kernel<<<4096, 256, 0, stream>>>(khvh, WkT, bk, gkw, gkb, kproj);
        conv_f16_kernel<<<4096, 256, 0, stream>>>(value, khvh, 8388608);
        gemm_f16_kernel<<<4096, 256, 0, stream>>>(khvh, Wv2T, bv2, gv2w, gv2b, vproj);
    } else {
        gemm_proj_kernel<<<4096, 256, 0, stream>>>(key,   WkT,  bk,  gkw,  gkb,  kproj);
        gemm_proj_kernel<<<4096, 256, 0, stream>>>(value, Wv2T, bv2, gv2w, gv2b, vproj);
    }
    attn_alpha_kernel<<<1024, 256, 0, stream>>>(kproj, q1, WmT, bm, Ws, bs,
                                                wsAlpha, wsPool);
    attn_soft_kernel<<<256, 256, 0, stream>>>(wsAlpha, wsPool, Wc, bc, wsAch);
    attn_agg_kernel<<<1024, 256, 0, stream>>>(vproj, wsAlpha, wsAggp);
    attn_out_kernel<<<128, 256, 0, stream>>>(wsAggp, wsAch, q2, out);
}

// Round 6
// 1032.436 us; speedup vs baseline: 1.4253x; 1.1005x over previous
//
#include <hip/hip_runtime.h>
#include <hip/hip_bf16.h>
#include <hip/hip_fp16.h>
#include <stdint.h>

typedef _Float16 hf;
typedef _Float16 h8 __attribute__((ext_vector_type(8)));
typedef float    f4 __attribute__((ext_vector_type(4)));
typedef uint32_t u4 __attribute__((ext_vector_type(4)));

__device__ __forceinline__ float celu_f(float x) {
    return x > 0.f ? x : 1.3f * expm1f(x * (1.0f / 1.3f));
}

__device__ __forceinline__ void gload_lds16(const void* g, void* l) {
    __builtin_amdgcn_global_load_lds(
        (const __attribute__((address_space(1))) void*)g,
        (__attribute__((address_space(3))) void*)l, 16, 0, 0);
}

// ---------------------------------------------------------------------------
// transpose + cast f32 -> f16:  dst[c][r] = (hf)src[r][c]
// ---------------------------------------------------------------------------
__global__ __launch_bounds__(256)
void transpose_cast_kernel(const float* __restrict__ src, hf* __restrict__ dst,
                           int R, int C) {
    __shared__ float tile[32][33];
    int nbx = C >> 5;
    int bx = blockIdx.x % nbx, by = blockIdx.x / nbx;
    int c0 = bx << 5, r0 = by << 5;
    int lx = threadIdx.x & 31, ly = threadIdx.x >> 5;   // 32 x 8
#pragma unroll
    for (int i = 0; i < 32; i += 8)
        tile[ly + i][lx] = src[(size_t)(r0 + ly + i) * C + c0 + lx];
    __syncthreads();
#pragma unroll
    for (int i = 0; i < 32; i += 8)
        dst[(size_t)(c0 + ly + i) * R + r0 + lx] = (hf)tile[lx][ly + i];
}

// ---------------------------------------------------------------------------
// small projections: q1 = GN(CELU(query@Wq+bq)), q2 = GN(CELU(query@Wv1+bv1))
// grid 256 = 2 proj x 32 rows x 4 col-chunks (GN group 128 stays block-local)
// ---------------------------------------------------------------------------
__global__ __launch_bounds__(256)
void small_proj_kernel(const float* __restrict__ query,
                       const float* __restrict__ W0, const float* __restrict__ b0,
                       const float* __restrict__ gw0, const float* __restrict__ gb0,
                       const float* __restrict__ W1, const float* __restrict__ b1,
                       const float* __restrict__ gw1, const float* __restrict__ gb1,
                       float* __restrict__ q1, float* __restrict__ q2) {
    int bid = blockIdx.x;
    int p = bid & 1, row = (bid >> 1) & 31, qc = bid >> 6;
    const float* W    = p ? W1  : W0;
    const float* bias = p ? b1  : b0;
    const float* gw   = p ? gw1 : gw0;
    const float* gb   = p ? gb1 : gb0;
    float* dst        = p ? q2  : q1;

    __shared__ float s_q[1024];
    __shared__ float s_ws[4], s_wq[4];
    int tid = threadIdx.x, lane = tid & 63, w = tid >> 6;
    int col = qc * 256 + tid;

#pragma unroll
    for (int i = 0; i < 4; ++i) s_q[tid + 256 * i] = query[row * 1024 + tid + 256 * i];
    __syncthreads();

    float acc = bias[col];
#pragma unroll 8
    for (int k = 0; k < 1024; ++k)
        acc = fmaf(s_q[k], W[(size_t)k * 1024 + col], acc);
    acc = celu_f(acc);

    float s = acc, sq = acc * acc;
#pragma unroll
    for (int off = 1; off < 64; off <<= 1) {
        s += __shfl_xor(s, off);
        sq += __shfl_xor(sq, off);
    }
    if (lane == 0) { s_ws[w] = s; s_wq[w] = sq; }
    __syncthreads();
    int lg = tid >> 7;  // local group (global group = 2*qc + lg)
    float mean = (s_ws[2 * lg] + s_ws[2 * lg + 1]) * (1.f / 128.f);
    float var  = (s_wq[2 * lg] + s_wq[2 * lg + 1]) * (1.f / 128.f) - mean * mean;
    float rs = rsqrtf(var + 1e-5f);
    dst[row * 1024 + col] = (acc - mean) * rs * gw[col] + gb[col];
}

// ---------------------------------------------------------------------------
// fused GEMM: A f32 [65536,1024] @ WT f16 [1024(n),1024(k)] + CELU + GroupNorm
// m97 structure: 128x128 tile, BK=64, 4 waves, single-buffer 2-barrier loop.
// A: reg-staged f32 -> cvt_pkrtz f16 -> ds_write_b128 into XOR-swizzled slot
//    (LDS[r][c8^(r&7)] holds global k-slot c8 — same mapping as B).
// B: global_load_lds w=16 with XOR-swizzled global source, linear LDS dest.
// Read path (validated R5, 0 bank conflicts): slot (kk*4+l4) ^ (row&7).
// ---------------------------------------------------------------------------
#define BM 128
#define BN 128
#define BK 64
#define NT 16

__global__ __launch_bounds__(256, 2)
void gemm_fused_kernel(const float* __restrict__ A, const hf* __restrict__ WT,
                       const float* __restrict__ bias,
                       const float* __restrict__ gw, const float* __restrict__ gb,
                       hf* __restrict__ out) {
    __shared__ hf As[BM][BK];        // 16 KB
    __shared__ hf Bs[BN][BK];        // 16 KB
    __shared__ float s_sum[2][BM];   // 1 KB
    __shared__ float s_sq[2][BM];    // 1 KB

    const int bid = blockIdx.x;
    const int l  = (bid & 7) * 512 + (bid >> 3);   // XCD-chunked swizzle (4096 % 8 == 0)
    const int tm = l >> 3, tn = l & 7;
    const int m0 = tm * BM, n0 = tn * BN;

    const int tid = threadIdx.x;
    const int lane = tid & 63, wid = tid >> 6;
    const int wr = wid >> 1, wc = wid & 1;
    const int l15 = lane & 15, l4 = lane >> 4;

    f4 acc[4][4];
#pragma unroll
    for (int mi = 0; mi < 4; ++mi)
#pragma unroll
        for (int ni = 0; ni < 4; ++ni) acc[mi][ni] = (f4)0.f;

    const float* Abase = A  + (size_t)m0 * 1024;
    const hf*    Bbase = WT + (size_t)n0 * 1024;

    // staging geometry (i-independent parts): 256 threads cover 1024 16B slots
    // idx = tid + 256*i -> row = (tid>>3) + 32*i, k-slot c8 = tid&7.
    // swizzled slot scs = c8 ^ (row&7); row&7 == (tid>>3)&7 for all i.
    const int r0  = tid >> 3;
    const int c8  = tid & 7;
    const int scs = c8 ^ (r0 & 7);

    for (int t = 0; t < NT; ++t) {
        const int kof = t * BK;
        // B: async direct-to-LDS, swizzled global source, linear dest
#pragma unroll
        for (int i = 0; i < 4; ++i)
            gload_lds16(Bbase + (size_t)(r0 + 32 * i) * 1024 + kof + scs * 8,
                        (char*)&Bs[0][0] + (size_t)(tid + 256 * i) * 16);
        // A: f32 load -> pack f16 -> ds_write into swizzled slot
#pragma unroll
        for (int i = 0; i < 4; ++i) {
            const float* ap = Abase + (size_t)(r0 + 32 * i) * 1024 + kof + c8 * 8;
            f4 x = *(const f4*)ap;
            f4 y = *(const f4*)(ap + 4);
            u4 pk;
            pk[0] = __builtin_bit_cast(uint32_t, __builtin_amdgcn_cvt_pkrtz(x[0], x[1]));
            pk[1] = __builtin_bit_cast(uint32_t, __builtin_amdgcn_cvt_pkrtz(x[2], x[3]));
            pk[2] = __builtin_bit_cast(uint32_t, __builtin_amdgcn_cvt_pkrtz(y[0], y[1]));
            pk[3] = __builtin_bit_cast(uint32_t, __builtin_amdgcn_cvt_pkrtz(y[2], y[3]));
            *(u4*)((char*)&As[0][0] + ((size_t)(r0 + 32 * i) * 8 + scs) * 16) = pk;
        }
        __syncthreads();

        h8 af[4][2], bf[4][2];
        const int sx = l15 & 7;   // read-side XOR (row&7)
#pragma unroll
        for (int mi = 0; mi < 4; ++mi)
#pragma unroll
            for (int kk = 0; kk < 2; ++kk) {
                int row = wr * 64 + mi * 16 + l15;
                int slot = (kk * 4 + l4) ^ sx;
                af[mi][kk] = *(const h8*)((const char*)&As[0][0] + row * 128 + slot * 16);
            }
#pragma unroll
        for (int ni = 0; ni < 4; ++ni)
#pragma unroll
            for (int kk = 0; kk < 2; ++kk) {
                int row = wc * 64 + ni * 16 + l15;
                int slot = (kk * 4 + l4) ^ sx;
                bf[ni][kk] = *(const h8*)((const char*)&Bs[0][0] + row * 128 + slot * 16);
            }
#pragma unroll
        for (int kk = 0; kk < 2; ++kk)
#pragma unroll
            for (int mi = 0; mi < 4; ++mi)
#pragma unroll
                for (int ni = 0; ni < 4; ++ni)
                    acc[mi][ni] = __builtin_amdgcn_mfma_f32_16x16x32_f16(
                        af[mi][kk], bf[ni][kk], acc[mi][ni], 0, 0, 0);
        __syncthreads();
    }

    // ---- epilogue: bias + CELU + GroupNorm (group 128 == tile width) ----
    float biasv[4], gwv[4], gbv[4];
#pragma unroll
    for (int ni = 0; ni < 4; ++ni) {
        int c = n0 + wc * 64 + ni * 16 + l15;
        biasv[ni] = bias[c]; gwv[ni] = gw[c]; gbv[ni] = gb[c];
    }
#pragma unroll
    for (int mi = 0; mi < 4; ++mi) {
#pragma unroll
        for (int reg = 0; reg < 4; ++reg) {
            float s = 0.f, q = 0.f;
#pragma unroll
            for (int ni = 0; ni < 4; ++ni) {
                float v = acc[mi][ni][reg] + biasv[ni];
                v = celu_f(v);
                acc[mi][ni][reg] = v;
                s += v; q += v * v;
            }
#pragma unroll
            for (int off = 1; off < 16; off <<= 1) {
                s += __shfl_xor(s, off);
                q += __shfl_xor(q, off);
            }
            if (l15 == 0) {
                int R = wr * 64 + mi * 16 + l4 * 4 + reg;
                s_sum[wc][R] = s;
                s_sq[wc][R]  = q;
            }
        }
    }
    __syncthreads();
    const int bb = m0 >> 11;
    hf* outbase = out + (((size_t)bb * 8 + tn) * 2048 + (m0 & 2047)) * 128;
#pragma unroll
    for (int mi = 0; mi < 4; ++mi) {
#pragma unroll
        for (int reg = 0; reg < 4; ++reg) {
            int R = wr * 64 + mi * 16 + l4 * 4 + reg;
            float mean = (s_sum[0][R] + s_sum[1][R]) * (1.f / 128.f);
            float var  = (s_sq[0][R] + s_sq[1][R]) * (1.f / 128.f) - mean * mean;
            float rs = rsqrtf(var + 1e-5f);
#pragma unroll
            for (int ni = 0; ni < 4; ++ni) {
                int d = wc * 64 + ni * 16 + l15;
                float y = (acc[mi][ni][reg] - mean) * rs * gwv[ni] + gbv[ni];
                outbase[(size_t)R * 128 + d] = (hf)y;
            }
        }
    }
}

// ---------------------------------------------------------------------------
// SCAtt stage 1: alpha (pre-softmax) + pool partials.
// grid 1024 = 256 bh x 4 M-chunks of 512; 256 thr.
// ---------------------------------------------------------------------------
__global__ __launch_bounds__(256)
void attn_alpha_kernel(const hf* __restrict__ kp, const float* __restrict__ q1,
                       const hf* __restrict__ WmT,
                       const float* __restrict__ bm, const float* __restrict__ Wsv,
                       const float* __restrict__ bsv,
                       float* __restrict__ ws_alpha, float* __restrict__ ws_pool) {
    const int bid = blockIdx.x;
    const int bh = bid >> 2, chunk = bid & 3;
    const int b = bh >> 3, h = bh & 7;
    const hf* kbh = kp + (size_t)bh * 2048 * 128;

    __shared__ float s_pool[4][64];
    const int tid = threadIdx.x, lane = tid & 63, w = tid >> 6;
    const int l15 = lane & 15, l4 = lane >> 4;

    h8 q1f[4], bfr[4][4];
    float bmv[4], wsw[4];
    const float* q1h = q1 + b * 1024 + h * 128;
#pragma unroll
    for (int kk = 0; kk < 4; ++kk)
#pragma unroll
        for (int j = 0; j < 8; ++j)
            q1f[kk][j] = (hf)q1h[kk * 32 + l4 * 8 + j];
#pragma unroll
    for (int ni = 0; ni < 4; ++ni) {
#pragma unroll
        for (int kk = 0; kk < 4; ++kk)
            bfr[ni][kk] = *(const h8*)(WmT + (size_t)(ni * 16 + l15) * 128 + kk * 32 + l4 * 8);
        bmv[ni] = bm[ni * 16 + l15];
        wsw[ni] = Wsv[ni * 16 + l15];
    }
    const float bs0 = bsv[0];

    float pool_acc[4] = {0.f, 0.f, 0.f, 0.f};
    for (int it = 0; it < 8; ++it) {
        const int mt0 = chunk * 512 + (it * 4 + w) * 16;
        const hf* kr = kbh + (size_t)(mt0 + l15) * 128 + l4 * 8;
        h8 af[4];
#pragma unroll
        for (int kk = 0; kk < 4; ++kk) {
            h8 kf = *(const h8*)(kr + kk * 32);
            af[kk] = kf * q1f[kk];
        }
        f4 acc[4];
#pragma unroll
        for (int ni = 0; ni < 4; ++ni) acc[ni] = (f4)0.f;
#pragma unroll
        for (int kk = 0; kk < 4; ++kk)
#pragma unroll
            for (int ni = 0; ni < 4; ++ni)
                acc[ni] = __builtin_amdgcn_mfma_f32_16x16x32_f16(af[kk], bfr[ni][kk], acc[ni], 0, 0, 0);
        float apart[4] = {0.f, 0.f, 0.f, 0.f};
#pragma unroll
        for (int ni = 0; ni < 4; ++ni)
#pragma unroll
            for (int reg = 0; reg < 4; ++reg) {
                float tt = fmaxf(acc[ni][reg] + bmv[ni], 0.f);
                apart[reg] += tt * wsw[ni];
                pool_acc[ni] += tt;
            }
#pragma unroll
        for (int reg = 0; reg < 4; ++reg) {
            float a = apart[reg];
            a += __shfl_xor(a, 1); a += __shfl_xor(a, 2);
            a += __shfl_xor(a, 4); a += __shfl_xor(a, 8);
            if (l15 == 0) ws_alpha[bh * 2048 + mt0 + l4 * 4 + reg] = a + bs0;
        }
    }
#pragma unroll
    for (int ni = 0; ni < 4; ++ni) {
        float pv = pool_acc[ni];
        pv += __shfl_xor(pv, 16); pv += __shfl_xor(pv, 32);
        if (lane < 16) s_pool[w][ni * 16 + lane] = pv;
    }
    __syncthreads();
    if (tid < 64)
        ws_pool[bid * 64 + tid] =
            s_pool[0][tid] + s_pool[1][tid] + s_pool[2][tid] + s_pool[3][tid];
}

// ---------------------------------------------------------------------------
// SCAtt stage 2: softmax over M (writes normalized probs in place) + channel
// gate sigmoid(pool@Wc+bc). grid 256 (one per bh).
// ---------------------------------------------------------------------------
__global__ __launch_bounds__(256)
void attn_soft_kernel(float* __restrict__ ws_alpha, const float* __restrict__ ws_pool,
                      const float* __restrict__ Wc, const float* __restrict__ bc,
                      float* __restrict__ ws_ach) {
    const int bh = blockIdx.x;
    __shared__ float s_a[2048];
    __shared__ float s_pool[64];
    __shared__ float s_red[4];
    const int tid = threadIdx.x, lane = tid & 63, w = tid >> 6;
    float* arow = ws_alpha + bh * 2048;

#pragma unroll
    for (int i = 0; i < 8; ++i) s_a[tid + 256 * i] = arow[tid + 256 * i];
    if (tid < 64)
        s_pool[tid] = (ws_pool[(bh * 4 + 0) * 64 + tid] + ws_pool[(bh * 4 + 1) * 64 + tid] +
                       ws_pool[(bh * 4 + 2) * 64 + tid] + ws_pool[(bh * 4 + 3) * 64 + tid]) *
                      (1.f / 2048.f);
    __syncthreads();

    float lm = -1e30f;
#pragma unroll
    for (int i = 0; i < 8; ++i) lm = fmaxf(lm, s_a[tid + 256 * i]);
#pragma unroll
    for (int off = 1; off < 64; off <<= 1) lm = fmaxf(lm, __shfl_xor(lm, off));
    if (lane == 0) s_red[w] = lm;
    __syncthreads();
    const float gmax = fmaxf(fmaxf(s_red[0], s_red[1]), fmaxf(s_red[2], s_red[3]));
    float ls = 0.f;
#pragma unroll
    for (int i = 0; i < 8; ++i) {
        int idx = tid + 256 * i;
        float e = expf(s_a[idx] - gmax);
        s_a[idx] = e;
        ls += e;
    }
#pragma unroll
    for (int off = 1; off < 64; off <<= 1) ls += __shfl_xor(ls, off);
    __syncthreads();
    if (lane == 0) s_red[w] = ls;
    __syncthreads();
    const float inv_sum = 1.f / (s_red[0] + s_red[1] + s_red[2] + s_red[3]);
#pragma unroll
    for (int i = 0; i < 8; ++i) {
        int idx = tid + 256 * i;
        arow[idx] = s_a[idx] * inv_sum;
    }
    if (tid < 128) {
        float a = bc[tid];
#pragma unroll 8
        for (int j = 0; j < 64; ++j) a += s_pool[j] * Wc[j * 128 + tid];
        ws_ach[bh * 128 + tid] = 1.f / (1.f + expf(-a));
    }
}

// ---------------------------------------------------------------------------
// SCAtt stage 3: partial weighted-V aggregation, vectorized (16 B/lane).
// grid 1024 = 256 bh x 4 chunks of 512 rows; 256 thr.
// thread t: d-slot (t&15)*8 (h8), row-group g = t>>4 -> rows g+16m, m<32.
// wave covers 4 consecutive rows x 256B = 1KB contiguous per load step.
// ---------------------------------------------------------------------------
__global__ __launch_bounds__(256)
void attn_agg_kernel(const hf* __restrict__ vp, const float* __restrict__ ws_probs,
                     float* __restrict__ ws_aggp) {
    const int bid = blockIdx.x;
    const int bh = bid >> 2, chunk = bid & 3;
    __shared__ float s_p[512];
    __shared__ float s_part[16][128];
    const int tid = threadIdx.x;

    s_p[tid]       = ws_probs[bh * 2048 + chunk * 512 + tid];
    s_p[tid + 256] = ws_probs[bh * 2048 + chunk * 512 + tid + 256];
    __syncthreads();

    const int ds = tid & 15, g = tid >> 4;
    const hf* vb = vp + (size_t)bh * 2048 * 128 + (size_t)chunk * 512 * 128
                      + (size_t)g * 128 + ds * 8;
    float a[8];
#pragma unroll
    for (int j = 0; j < 8; ++j) a[j] = 0.f;
#pragma unroll 4
    for (int m = 0; m < 32; ++m) {
        float p = s_p[g + 16 * m];
        h8 v = *(const h8*)(vb + (size_t)m * 16 * 128);
#pragma unroll
        for (int j = 0; j < 8; ++j) a[j] = fmaf(p, (float)v[j], a[j]);
    }
#pragma unroll
    for (int j = 0; j < 8; ++j) s_part[g][ds * 8 + j] = a[j];
    __syncthreads();
    if (tid < 128) {
        float s = 0.f;
#pragma unroll
        for (int gg = 0; gg < 16; ++gg) s += s_part[gg][tid];
        ws_aggp[bid * 128 + tid] = s;
    }
}

// ---------------------------------------------------------------------------
// SCAtt stage 4: combine partials, apply q2 * agg * ach. grid 128.
// ---------------------------------------------------------------------------
__global__ __launch_bounds__(256)
void attn_out_kernel(const float* __restrict__ ws_aggp, const float* __restrict__ ws_ach,
                     const float* __restrict__ q2, float* __restrict__ out) {
    const int idx = blockIdx.x * 256 + threadIdx.x;   // 32768 outputs
    const int b = idx >> 10, c = idx & 1023;
    const int h = c >> 7, d = c & 127;
    const int bh = b * 8 + h;
    float agg = ws_aggp[(bh * 4 + 0) * 128 + d] + ws_aggp[(bh * 4 + 1) * 128 + d] +
                ws_aggp[(bh * 4 + 2) * 128 + d] + ws_aggp[(bh * 4 + 3) * 128 + d];
    out[idx] = q2[idx] * agg * ws_ach[bh * 128 + d];
}

// ---------------------------------------------------------------------------
extern "C" void kernel_launch(void* const* d_in, const int* in_sizes, int n_in,
                              void* d_out, int out_size, void* d_ws, size_t ws_size,
                              hipStream_t stream) {
    const float* query = (const float*)d_in[0];
    const float* key   = (const float*)d_in[1];
    const float* value = (const float*)d_in[2];
    const float* Wq   = (const float*)d_in[3];
    const float* bq   = (const float*)d_in[4];
    const float* gqw  = (const float*)d_in[5];
    const float* gqb  = (const float*)d_in[6];
    const float* Wv1  = (const float*)d_in[7];
    const float* bv1  = (const float*)d_in[8];
    const float* gv1w = (const float*)d_in[9];
    const float* gv1b = (const float*)d_in[10];
    const float* Wk   = (const float*)d_in[11];
    const float* bk   = (const float*)d_in[12];
    const float* gkw  = (const float*)d_in[13];
    const float* gkb  = (const float*)d_in[14];
    const float* Wv2  = (const float*)d_in[15];
    const float* bv2  = (const float*)d_in[16];
    const float* gv2w = (const float*)d_in[17];
    const float* gv2b = (const float*)d_in[18];
    const float* Wm   = (const float*)d_in[19];
    const float* bm   = (const float*)d_in[20];
    const float* Ws   = (const float*)d_in[21];
    const float* bs   = (const float*)d_in[22];
    const float* Wc   = (const float*)d_in[23];
    const float* bc   = (const float*)d_in[24];
    float* out = (float*)d_out;

    char* ws = (char*)d_ws;
    const size_t SZ_PROJ = 134217728;   // 65536*1024 hf
    hf*   kproj = (hf*)(ws);
    hf*   vproj = (hf*)(ws + SZ_PROJ);
    char* tail  = ws + 2 * SZ_PROJ;     // total need ~276 MB (R5 ran fast path => ws >= 400 MB)

    float* q1      = (float*)(tail);                   // 131072 B
    float* q2      = (float*)(tail + 131072);          // 131072 B
    hf*    WkT     = (hf*)(tail + 262144);             // 2 MB
    hf*    Wv2T    = (hf*)(tail + 2359296);            // 2 MB
    hf*    WmT     = (hf*)(tail + 4456448);            // 16 KB
    float* wsAlpha = (float*)(tail + 4472832);         // 2 MB  (alpha -> probs)
    float* wsPool  = (float*)(tail + 6569984);         // 256 KB
    float* wsAch   = (float*)(tail + 6832128);         // 128 KB
    float* wsAggp  = (float*)(tail + 6963200);         // 512 KB

    transpose_cast_kernel<<<1024, 256, 0, stream>>>(Wk,  WkT,  1024, 1024);
    transpose_cast_kernel<<<1024, 256, 0, stream>>>(Wv2, Wv2T, 1024, 1024);
    transpose_cast_kernel<<<8,    256, 0, stream>>>(Wm,  WmT,  128,  64);
    small_proj_kernel<<<256, 256, 0, stream>>>(query, Wq, bq, gqw, gqb,
                                               Wv1, bv1, gv1w, gv1b, q1, q2);
    gemm_fused_kernel<<<4096, 256, 0, stream>>>(key,   WkT,  bk,  gkw,  gkb,  kproj);
    gemm_fused_kernel<<<4096, 256, 0, stream>>>(value, Wv2T, bv2, gv2w, gv2b, vproj);
    attn_alpha_kernel<<<1024, 256, 0, stream>>>(kproj, q1, WmT, bm, Ws, bs,
                                                wsAlpha, wsPool);
    attn_soft_kernel<<<256, 256, 0, stream>>>(wsAlpha, wsPool, Wc, bc, wsAch);
    attn_agg_kernel<<<1024, 256, 0, stream>>>(vproj, wsAlpha, wsAggp);
    attn_out_kernel<<<128, 256, 0, stream>>>(wsAggp, wsAch, q2, out);
}